// Round 10
// baseline (5715.706 us; speedup 1.0000x reference)
//
#include <hip/hip_runtime.h>
#include <math.h>

// Problem constants
#define B_    32
#define CIN   4
#define SLEN  2048
#define NF    256
#define HD    256          // LSTM hidden per direction
#define SP    341          // post conv+pool sequence length
#define RTOT  (B_*SP)      // 10912 rows
#define NH_   8
#define DH_   64
#define GRP   4            // batches per attention group
#define PSTR  344          // padded P row stride (16B-aligned)

typedef __attribute__((ext_vector_type(8))) short short8;
typedef __attribute__((ext_vector_type(4))) float floatx4;

__device__ __forceinline__ float sigmoidf_(float x) { return 1.0f / (1.0f + expf(-x)); }

__device__ __forceinline__ unsigned short f2bf(float x) {
    unsigned int u = __float_as_uint(x);
    unsigned int r = (u + 0x7FFF + ((u >> 16) & 1)) >> 16;   // RNE
    return (unsigned short)r;
}
__device__ __forceinline__ float bf2f(unsigned short b) {
    return __uint_as_float(((unsigned int)b) << 16);
}

// ---------------------------------------------------------------------------
// Kernel 1: Conv1d(4->256,k13,pad6) + BN(eval) + ReLU + MaxPool1d(6) -> x0[b*341+s][co]
// ---------------------------------------------------------------------------
__global__ __launch_bounds__(256)
void conv_pool_k(const float* __restrict__ in, const float* __restrict__ cw,
                 const float* __restrict__ gamma, const float* __restrict__ beta,
                 float* __restrict__ x0)
{
    const int b  = blockIdx.y;
    const int s0 = blockIdx.x * 16;
    const int co = threadIdx.x;
    __shared__ float ins[CIN][16*6 + 12];
    for (int idx = threadIdx.x; idx < CIN*108; idx += 256) {
        int ci = idx / 108, o = idx % 108;
        int pos = 6*s0 - 6 + o;
        ins[ci][o] = (pos >= 0 && pos < SLEN) ? in[(b*CIN + ci)*SLEN + pos] : 0.0f;
    }
    float wreg[52];
    {
        const float4* wp = (const float4*)(cw + co*52);
        #pragma unroll
        for (int j4 = 0; j4 < 13; ++j4) {
            float4 w4 = wp[j4];
            wreg[j4*4+0]=w4.x; wreg[j4*4+1]=w4.y; wreg[j4*4+2]=w4.z; wreg[j4*4+3]=w4.w;
        }
    }
    const float scale = gamma[co] * (1.0f / sqrtf(1.0f + 1e-5f));
    const float shift = beta[co];
    __syncthreads();
    for (int si = 0; si < 16; ++si) {
        int s = s0 + si;
        if (s >= SP) break;
        float win[CIN][18];
        #pragma unroll
        for (int ci = 0; ci < CIN; ++ci)
            #pragma unroll
            for (int o = 0; o < 18; ++o)
                win[ci][o] = ins[ci][6*si + o];
        float m = -1e30f;
        #pragma unroll
        for (int p6 = 0; p6 < 6; ++p6) {
            float acc = 0.0f;
            #pragma unroll
            for (int ci = 0; ci < CIN; ++ci)
                #pragma unroll
                for (int kk = 0; kk < 13; ++kk)
                    acc += win[ci][p6+kk] * wreg[ci*13+kk];
            float val = acc * scale + shift;
            val = fmaxf(val, 0.0f);
            m = fmaxf(m, val);
        }
        x0[(size_t)(b*SP + s)*NF + co] = m;
    }
}

// ---------------------------------------------------------------------------
// Kernel 2: generic fp32 GEMM  C[M,N] = act(A[M,K] @ Bw[N,K]^T + bias[N])
// ---------------------------------------------------------------------------
template<int RELU>
__global__ __launch_bounds__(256)
void gemm_k(const float* __restrict__ A, const float* __restrict__ Bw,
            const float* __restrict__ bias, float* __restrict__ C,
            int M, int N, int K)
{
    const int n0 = blockIdx.x * 128;
    const int m0 = blockIdx.y * 128;
    const int tid = threadIdx.x;
    const int tx = tid % 16, ty = tid / 16;
    __shared__ float As[16][132];
    __shared__ float Bs[16][132];
    float acc[8][8];
    #pragma unroll
    for (int i = 0; i < 8; ++i)
        #pragma unroll
        for (int j = 0; j < 8; ++j) acc[i][j] = 0.0f;

    const int lr = tid >> 1;
    const int lc = (tid & 1) * 8;

    for (int k0 = 0; k0 < K; k0 += 16) {
        {
            int gm = m0 + lr; if (gm >= M) gm = M - 1;
            const float* ap = A + (size_t)gm*K + k0 + lc;
            float4 v0 = *(const float4*)ap;
            float4 v1 = *(const float4*)(ap + 4);
            As[lc+0][lr]=v0.x; As[lc+1][lr]=v0.y; As[lc+2][lr]=v0.z; As[lc+3][lr]=v0.w;
            As[lc+4][lr]=v1.x; As[lc+5][lr]=v1.y; As[lc+6][lr]=v1.z; As[lc+7][lr]=v1.w;
            const float* bp = Bw + (size_t)(n0 + lr)*K + k0 + lc;
            float4 u0 = *(const float4*)bp;
            float4 u1 = *(const float4*)(bp + 4);
            Bs[lc+0][lr]=u0.x; Bs[lc+1][lr]=u0.y; Bs[lc+2][lr]=u0.z; Bs[lc+3][lr]=u0.w;
            Bs[lc+4][lr]=u1.x; Bs[lc+5][lr]=u1.y; Bs[lc+6][lr]=u1.z; Bs[lc+7][lr]=u1.w;
        }
        __syncthreads();
        #pragma unroll
        for (int k = 0; k < 16; ++k) {
            float4 a0 = *(const float4*)&As[k][ty*4];
            float4 a1 = *(const float4*)&As[k][ty*4 + 64];
            float4 b0 = *(const float4*)&Bs[k][tx*4];
            float4 b1 = *(const float4*)&Bs[k][tx*4 + 64];
            float av[8] = {a0.x,a0.y,a0.z,a0.w,a1.x,a1.y,a1.z,a1.w};
            float bv[8] = {b0.x,b0.y,b0.z,b0.w,b1.x,b1.y,b1.z,b1.w};
            #pragma unroll
            for (int i = 0; i < 8; ++i)
                #pragma unroll
                for (int j = 0; j < 8; ++j)
                    acc[i][j] += av[i] * bv[j];
        }
        __syncthreads();
    }
    #pragma unroll
    for (int ih = 0; ih < 2; ++ih) {
        #pragma unroll
        for (int ii = 0; ii < 4; ++ii) {
            int m = m0 + ih*64 + ty*4 + ii;
            if (m >= M) continue;
            #pragma unroll
            for (int jh = 0; jh < 2; ++jh) {
                int n = n0 + jh*64 + tx*4;
                float4 bb = *(const float4*)&bias[n];
                float4 r;
                r.x = acc[ih*4+ii][jh*4+0] + bb.x;
                r.y = acc[ih*4+ii][jh*4+1] + bb.y;
                r.z = acc[ih*4+ii][jh*4+2] + bb.z;
                r.w = acc[ih*4+ii][jh*4+3] + bb.w;
                if (RELU) {
                    r.x = fmaxf(r.x, 0.f); r.y = fmaxf(r.y, 0.f);
                    r.z = fmaxf(r.z, 0.f); r.w = fmaxf(r.w, 0.f);
                }
                *(float4*)&C[(size_t)m*N + n] = r;
            }
        }
    }
}

// ---------------------------------------------------------------------------
// Kernel 3a: pack Whh -> bf16 hi/lo in MFMA B-FRAGMENT order (per layer).
// Wp[d][jt][kk][p][lane][8]: jt in [0,64) = 16-col gate subtile, kk in [0,8),
// p in {hi,lo}; fragment elem = W[d][jt*16+(lane&15)][kk*32+(lane>>4)*8 + e].
// Thread i handles 8 ushorts: rem = jt*1024+kk*128+p*64+lane -> dst = rem*8
// (== jt*8192 + kk*1024 + p*512 + lane*8 -- stride identity, no remap).
// ---------------------------------------------------------------------------
__global__ __launch_bounds__(256)
void pack_wfrag_k(const float* __restrict__ W, unsigned short* __restrict__ Wp)
{
    int i = blockIdx.x*256 + threadIdx.x;      // [0, 131072)
    int d = i >> 16;
    int rem = i & 65535;
    int lane = rem & 63;
    int p    = (rem >> 6) & 1;
    int kk   = (rem >> 7) & 7;
    int jt   = rem >> 10;
    int grow = jt*16 + (lane & 15);
    int kbase = kk*32 + (lane >> 4)*8;
    const float* src = W + ((size_t)d*1024 + grow)*256 + kbase;
    unsigned short v[8];
    #pragma unroll
    for (int e = 0; e < 8; ++e) {
        float x = src[e];
        unsigned short h = f2bf(x);
        v[e] = p ? f2bf(x - bf2f(h)) : h;
    }
    unsigned short* dst = Wp + (size_t)d*524288 + (size_t)rem*8;
    *(uint4*)dst = *(const uint4*)v;
}

// ---------------------------------------------------------------------------
// Kernel 3b: SELF-CONTAINED LSTM scan. Grid (11 m-tiles, 2 dirs) = 22 blocks
// x 512 thr (8 waves). Each block owns 32 m-rows x ALL 1024 gate cols x all 32
// steps: h lives in LDS (bf16 hi/lo, 2 parities, 66 KB), c in registers ->
// ZERO inter-block sync, zero global h traffic, zero fences (R9 post-mortem:
// the cross-block h exchange was the 18 us/step floor). W streams from L2 in
// fragment order (coalesced 1KB loads); mhalf-paired waves share B streams
// (L1 reuse). G prefetched into the MFMA shadow. Math bit-identical to R6/R9.
// ---------------------------------------------------------------------------
__global__ __launch_bounds__(512, 1)
void lstm_scan_k(const float* __restrict__ G,              // [32*341][2048]
                 const unsigned short* __restrict__ Wp,    // packed frags, 2 dirs
                 float* __restrict__ x_out)                // [32*341][512]
{
    __shared__ unsigned short hhi[2][32][264];
    __shared__ unsigned short hlo[2][32][264];

    const int m0 = blockIdx.x * 32;
    const int d  = blockIdx.y;
    const int tid = threadIdx.x;
    const int w = tid >> 6, lane = tid & 63;
    const int mhalf = w & 1, jhg = w >> 1;      // wave = (mhalf, 4-jh group)
    const int ln15 = lane & 15, lq = lane >> 4;

    // init both h parities to 0 (rows >= SP stay 0 forever)
    for (int idx = tid; idx < 2*32*264; idx += 512) {
        int p = idx / (32*264), r2 = idx % (32*264);
        hhi[p][r2/264][r2%264] = 0;
        hlo[p][r2/264][r2%264] = 0;
    }
    __syncthreads();

    const unsigned short* WpD = Wp + (size_t)d*524288;
    const int mloc_a = mhalf*16 + ln15;          // A-frag local row
    const int mbase  = m0 + mhalf*16 + lq*4;     // epilogue global row base

    float creg[4][4];                            // c state: [jh-local][r]
    #pragma unroll
    for (int a = 0; a < 4; ++a)
        #pragma unroll
        for (int b = 0; b < 4; ++b) creg[a][b] = 0.f;

    for (int s = 0; s < B_; ++s) {
        const int t_in = d ? (B_-1-s) : s;
        const int rp = s & 1, wpar = rp ^ 1;

        // A-frags for this wave's mhalf: 8 kk, hi/lo (from LDS)
        short8 Ah[8], Al[8];
        #pragma unroll
        for (int kk = 0; kk < 8; ++kk) {
            int ko = kk*32 + lq*8;
            Ah[kk] = *(const short8*)&hhi[rp][mloc_a][ko];
            Al[kk] = *(const short8*)&hlo[rp][mloc_a][ko];
        }

        #pragma unroll
        for (int jl = 0; jl < 4; ++jl) {
            const int jh = jhg*4 + jl;
            const int col = jh*16 + ln15;

            // G prefetch (hidden under the MFMA stream)
            float gpre[4][4];
            #pragma unroll
            for (int r = 0; r < 4; ++r) {
                int m = mbase + r;
                int mc = m < SP ? m : SP-1;
                size_t gb = ((size_t)t_in*SP + mc)*2048 + (size_t)d*1024 + col;
                gpre[0][r] = G[gb];
                gpre[1][r] = G[gb + 256];
                gpre[2][r] = G[gb + 512];
                gpre[3][r] = G[gb + 768];
            }

            floatx4 acc[4];
            #pragma unroll
            for (int g = 0; g < 4; ++g) acc[g] = (floatx4){0.f,0.f,0.f,0.f};
            #pragma unroll
            for (int g = 0; g < 4; ++g) {
                const unsigned short* fb = WpD + (size_t)(g*16 + jh)*8192 + (size_t)lane*8;
                #pragma unroll
                for (int kk = 0; kk < 8; ++kk) {
                    short8 Bh = *(const short8*)(fb + kk*1024);
                    short8 Bl = *(const short8*)(fb + kk*1024 + 512);
                    acc[g] = __builtin_amdgcn_mfma_f32_16x16x32_bf16(Al[kk], Bh, acc[g], 0, 0, 0);
                    acc[g] = __builtin_amdgcn_mfma_f32_16x16x32_bf16(Ah[kk], Bl, acc[g], 0, 0, 0);
                    acc[g] = __builtin_amdgcn_mfma_f32_16x16x32_bf16(Ah[kk], Bh, acc[g], 0, 0, 0);
                }
            }

            // epilogue: all 4 gates for (m, col) live in this lane's registers
            #pragma unroll
            for (int r = 0; r < 4; ++r) {
                int m = mbase + r;
                float gi = acc[0][r] + gpre[0][r];
                float gf = acc[1][r] + gpre[1][r];
                float gg = acc[2][r] + gpre[2][r];
                float go = acc[3][r] + gpre[3][r];
                float cn = sigmoidf_(gf)*creg[jl][r] + sigmoidf_(gi)*tanhf(gg);
                creg[jl][r] = cn;
                float hv = sigmoidf_(go)*tanhf(cn);
                if (m < SP) {
                    unsigned short hb16 = f2bf(hv);
                    unsigned short lb16 = f2bf(hv - bf2f(hb16));
                    int mloc = mhalf*16 + lq*4 + r;
                    x_out[((size_t)t_in*SP + m)*512 + d*256 + col] = hv;
                    hhi[wpar][mloc][col] = hb16;
                    hlo[wpar][mloc][col] = lb16;
                }
            }
        }
        __syncthreads();   // h parity wpar complete -> next step reads it
    }
}

// ---------------------------------------------------------------------------
// Kernel 4a: scores tile (64x64), RPE analytic.
// ---------------------------------------------------------------------------
__global__ __launch_bounds__(256)
void scores_k(const float* __restrict__ q, const float* __restrict__ k,
              float* __restrict__ P, int g)
{
    const int h = blockIdx.z, bl = blockIdx.y, bg = g*GRP + bl;
    const int q0 = (blockIdx.x / 6) * 64;
    const int k0 = (blockIdx.x % 6) * 64;
    const int tid = threadIdx.x;
    __shared__ float qs[64][68];
    __shared__ float ks[64][68];
    {
        int jr = tid >> 2, c16 = (tid & 3) * 16;
        int qq = q0 + jr; if (qq > SP-1) qq = SP-1;
        int kr = k0 + jr; if (kr > SP-1) kr = SP-1;
        const float* qp = &q[((size_t)bg*SP + qq)*512 + h*64 + c16];
        const float* kp = &k[((size_t)bg*SP + kr)*512 + h*64 + c16];
        #pragma unroll
        for (int u = 0; u < 4; ++u) {
            *(float4*)&qs[jr][c16 + u*4] = *(const float4*)(qp + u*4);
            *(float4*)&ks[jr][c16 + u*4] = *(const float4*)(kp + u*4);
        }
    }
    __syncthreads();
    const int tx = tid & 15, ty = tid >> 4;
    float acc[4][4];
    #pragma unroll
    for (int i = 0; i < 4; ++i)
        #pragma unroll
        for (int j = 0; j < 4; ++j) acc[i][j] = 0.0f;
    for (int d4 = 0; d4 < 64; d4 += 4) {
        float4 a[4], b[4];
        #pragma unroll
        for (int i = 0; i < 4; ++i) a[i] = *(const float4*)&qs[ty + 16*i][d4];
        #pragma unroll
        for (int j = 0; j < 4; ++j) b[j] = *(const float4*)&ks[tx + 16*j][d4];
        #pragma unroll
        for (int i = 0; i < 4; ++i)
            #pragma unroll
            for (int j = 0; j < 4; ++j)
                acc[i][j] += a[i].x*b[j].x + a[i].y*b[j].y + a[i].z*b[j].z + a[i].w*b[j].w;
    }
    #pragma unroll
    for (int i = 0; i < 4; ++i) {
        int qq = q0 + ty + 16*i;
        if (qq >= SP) continue;
        int r0 = 6*qq - 1; if (r0 < 0) r0 = 0;
        int r1 = 6*qq + 7; if (r1 > SLEN-1) r1 = SLEN-1;
        size_t rowb = ((size_t)(h*GRP + bl)*SP + qq) * PSTR;
        #pragma unroll
        for (int j = 0; j < 4; ++j) {
            int kk = k0 + tx + 16*j;
            if (kk >= SP) continue;
            int c0 = 6*kk - 1; if (c0 < 0) c0 = 0;
            int c1 = 6*kk + 7;
            int dd1 = c1 - r0; if (dd1 < 0) dd1 = -dd1;
            int dd2 = r1 - c0; if (dd2 < 0) dd2 = -dd2;
            int den = dd1 > dd2 ? dd1 : dd2;
            P[rowb + kk] = (acc[i][j] * 0.125f) * 2047.0f / (float)den;
        }
    }
}

// ---------------------------------------------------------------------------
// Kernel 4b: row softmax in place.
// ---------------------------------------------------------------------------
__global__ __launch_bounds__(256)
void softmax_k(float* __restrict__ P)
{
    const int tid = threadIdx.x;
    const int row = blockIdx.x * 4 + (tid >> 6);
    const int lane = tid & 63;
    float* rp = P + (size_t)row * PSTR;
    float v[6];
    float m = -1e30f;
    #pragma unroll
    for (int i = 0; i < 6; ++i) {
        int col = lane + 64*i;
        v[i] = (col < SP) ? rp[col] : -1e30f;
        m = fmaxf(m, v[i]);
    }
    #pragma unroll
    for (int o = 1; o < 64; o <<= 1) m = fmaxf(m, __shfl_xor(m, o, 64));
    float s = 0.0f;
    #pragma unroll
    for (int i = 0; i < 6; ++i) {
        v[i] = expf(v[i] - m);
        s += v[i];
    }
    #pragma unroll
    for (int o = 1; o < 64; o <<= 1) s += __shfl_xor(s, o, 64);
    float inv = 1.0f / s;
    #pragma unroll
    for (int i = 0; i < 6; ++i) {
        int col = lane + 64*i;
        if (col < SP) rp[col] = v[i] * inv;
    }
}

// ---------------------------------------------------------------------------
// Kernel 4c: out = relu(P @ V), K=SP in 6x64 chunks.
// ---------------------------------------------------------------------------
__global__ __launch_bounds__(256)
void pv_k(const float* __restrict__ P, const float* __restrict__ v,
          float* __restrict__ cat, int g)
{
    const int h = blockIdx.z, bl = blockIdx.y, bg = g*GRP + bl;
    const int q0 = blockIdx.x * 64;
    const int tid = threadIdx.x;
    __shared__ float ps[64][68];
    __shared__ float vs[64][68];
    const int tx = tid & 15, ty = tid >> 4;
    float acc[4][4];
    #pragma unroll
    for (int i = 0; i < 4; ++i)
        #pragma unroll
        for (int j = 0; j < 4; ++j) acc[i][j] = 0.0f;

    for (int kc = 0; kc < 6; ++kc) {
        const int kk0 = kc * 64;
        {
            int jr = tid >> 2, c16 = (tid & 3) * 16;
            int qq = q0 + jr; if (qq > SP-1) qq = SP-1;
            const float* pp = P + ((size_t)(h*GRP + bl)*SP + qq)*PSTR + kk0 + c16;
            #pragma unroll
            for (int u = 0; u < 4; ++u) {
                float4 w = *(const float4*)(pp + u*4);
                int klb = c16 + u*4;
                float vals[4] = {w.x, w.y, w.z, w.w};
                #pragma unroll
                for (int e = 0; e < 4; ++e)
                    ps[klb + e][jr] = (kk0 + klb + e < SP) ? vals[e] : 0.0f;
            }
        }
        {
            int jr = tid >> 2, c16 = (tid & 3) * 16;
            int kr = kk0 + jr; if (kr > SP-1) kr = SP-1;
            const float* vp = &v[((size_t)bg*SP + kr)*512 + h*64 + c16];
            #pragma unroll
            for (int u = 0; u < 4; ++u)
                *(float4*)&vs[jr][c16 + u*4] = *(const float4*)(vp + u*4);
        }
        __syncthreads();
        for (int kk = 0; kk < 64; ++kk) {
            float4 a4 = *(const float4*)&ps[kk][ty*4];
            float4 b4 = *(const float4*)&vs[kk][tx*4];
            float av[4] = {a4.x, a4.y, a4.z, a4.w};
            float bv[4] = {b4.x, b4.y, b4.z, b4.w};
            #pragma unroll
            for (int i = 0; i < 4; ++i)
                #pragma unroll
                for (int j = 0; j < 4; ++j)
                    acc[i][j] += av[i] * bv[j];
        }
        __syncthreads();
    }
    #pragma unroll
    for (int i = 0; i < 4; ++i) {
        int qq = q0 + ty*4 + i;
        if (qq >= SP) continue;
        float4 r;
        r.x = fmaxf(acc[i][0], 0.0f);
        r.y = fmaxf(acc[i][1], 0.0f);
        r.z = fmaxf(acc[i][2], 0.0f);
        r.w = fmaxf(acc[i][3], 0.0f);
        *(float4*)&cat[((size_t)bg*SP + qq)*512 + h*64 + tx*4] = r;
    }
}

// ---------------------------------------------------------------------------
extern "C" void kernel_launch(void* const* d_in, const int* in_sizes, int n_in,
                              void* d_out, int out_size, void* d_ws, size_t ws_size,
                              hipStream_t stream)
{
    (void)in_sizes; (void)n_in; (void)out_size; (void)ws_size;
    const float* in    = (const float*)d_in[0];
    const float* cw    = (const float*)d_in[1];
    const float* gamma = (const float*)d_in[2];
    const float* beta  = (const float*)d_in[3];
    const float* Wih0  = (const float*)d_in[4];
    const float* Whh0  = (const float*)d_in[5];
    const float* b0    = (const float*)d_in[6];
    const float* Wih1  = (const float*)d_in[7];
    const float* Whh1  = (const float*)d_in[8];
    const float* b1    = (const float*)d_in[9];
    const float* Qw    = (const float*)d_in[10];
    const float* Qb    = (const float*)d_in[11];
    const float* Kw    = (const float*)d_in[12];
    const float* Kb    = (const float*)d_in[13];
    const float* Vw    = (const float*)d_in[14];
    const float* Vb    = (const float*)d_in[15];
    const float* mhw   = (const float*)d_in[16];
    const float* mhb   = (const float*)d_in[17];
    float* out = (float*)d_out;

    // workspace arena (floats). Total 147.36 MB — EXACT R3/R6 memory map.
    float* x0 = (float*)d_ws;                                   //  2,793,472 f (W packs live here after use)
    float* G  = x0 + (size_t)RTOT*NF;                           // 22,347,776 f (reused q,k,v + P)
    float* x1 = G  + (size_t)RTOT*2048;                         //  5,586,944 f (reused cat)
    float* x2 = x1 + (size_t)RTOT*512;                          //  5,586,944 f
    float* hb = x2 + (size_t)RTOT*512;                          //  (unused now)
    (void)hb;
    // packed-fragment Whh arrays in x0's space (x0 dead after the first G-GEMM):
    unsigned short* wp0 = (unsigned short*)x0;                  // 2 MB (2 dirs x 1 MB)
    unsigned short* wp1 = wp0 + (size_t)2*524288;               // 2 MB; total 4 MB < 11.17 MB
    float* qbuf = G;
    float* kbuf = G + (size_t)RTOT*512;
    float* vbuf = G + (size_t)2*RTOT*512;
    float* P    = G + (size_t)3*RTOT*512;
    float* cat  = x1;

    // 1. conv+bn+relu+pool
    conv_pool_k<<<dim3(22, B_), 256, 0, stream>>>(in, cw, gamma, beta, x0);
    // 2. layer-1 input gates: G = x0 @ Wih0^T + b0  (consumes x0)
    gemm_k<0><<<dim3(16, 86), 256, 0, stream>>>(x0, Wih0, b0, G, RTOT, 2048, 256);
    // 2b. pack Whh -> fragment-order bf16 hi/lo (stream-ordered after gemm#1)
    pack_wfrag_k<<<dim3(512), 256, 0, stream>>>(Whh0, wp0);
    pack_wfrag_k<<<dim3(512), 256, 0, stream>>>(Whh1, wp1);
    // 3. layer-1 self-contained scan (no memsets, no barriers, no global h)
    lstm_scan_k<<<dim3(11, 2), 512, 0, stream>>>(G, wp0, x1);
    // 4. layer-2 input gates
    gemm_k<0><<<dim3(16, 86), 256, 0, stream>>>(x1, Wih1, b1, G, RTOT, 2048, 512);
    // 5. layer-2 scan
    lstm_scan_k<<<dim3(11, 2), 512, 0, stream>>>(G, wp1, x2);
    // 6. Q/K/V projections
    gemm_k<0><<<dim3(4, 86), 256, 0, stream>>>(x2, Qw, Qb, qbuf, RTOT, 512, 512);
    gemm_k<0><<<dim3(4, 86), 256, 0, stream>>>(x2, Kw, Kb, kbuf, RTOT, 512, 512);
    gemm_k<0><<<dim3(4, 86), 256, 0, stream>>>(x2, Vw, Vb, vbuf, RTOT, 512, 512);
    // 7. attention in GRP-batch groups
    for (int g = 0; g < B_/GRP; ++g) {
        scores_k <<<dim3(36, GRP, NH_), 256, 0, stream>>>(qbuf, kbuf, P, g);
        softmax_k<<<dim3(NH_*GRP*SP/4), 256, 0, stream>>>(P);
        pv_k     <<<dim3(6, GRP, NH_), 256, 0, stream>>>(P, vbuf, cat, g);
    }
    // 8. final linear + relu
    gemm_k<1><<<dim3(4, 86), 256, 0, stream>>>(cat, mhw, mhb, out, RTOT, 512, 512);
}

// Round 11
// 2254.061 us; speedup vs baseline: 2.5357x; 2.5357x over previous
//
#include <hip/hip_runtime.h>
#include <math.h>

// Problem constants
#define B_    32
#define CIN   4
#define SLEN  2048
#define NF    256
#define HD    256          // LSTM hidden per direction
#define SP    341          // post conv+pool sequence length
#define RTOT  (B_*SP)      // 10912 rows
#define NH_   8
#define DH_   64
#define GRP   4            // batches per attention group
#define PSTR  344          // padded P row stride (16B-aligned)
#define HS    (SP*HD)      // 87296: per-dir h elems

typedef __attribute__((ext_vector_type(8))) short short8;
typedef __attribute__((ext_vector_type(4))) float floatx4;

__device__ __forceinline__ float sigmoidf_(float x) { return 1.0f / (1.0f + expf(-x)); }

__device__ __forceinline__ unsigned short f2bf(float x) {
    unsigned int u = __float_as_uint(x);
    unsigned int r = (u + 0x7FFF + ((u >> 16) & 1)) >> 16;   // RNE
    return (unsigned short)r;
}
__device__ __forceinline__ float bf2f(unsigned short b) {
    return __uint_as_float(((unsigned int)b) << 16);
}

// ---------------------------------------------------------------------------
// Kernel 1: Conv1d(4->256,k13,pad6) + BN(eval) + ReLU + MaxPool1d(6) -> x0[b*341+s][co]
// ---------------------------------------------------------------------------
__global__ __launch_bounds__(256)
void conv_pool_k(const float* __restrict__ in, const float* __restrict__ cw,
                 const float* __restrict__ gamma, const float* __restrict__ beta,
                 float* __restrict__ x0)
{
    const int b  = blockIdx.y;
    const int s0 = blockIdx.x * 16;
    const int co = threadIdx.x;
    __shared__ float ins[CIN][16*6 + 12];
    for (int idx = threadIdx.x; idx < CIN*108; idx += 256) {
        int ci = idx / 108, o = idx % 108;
        int pos = 6*s0 - 6 + o;
        ins[ci][o] = (pos >= 0 && pos < SLEN) ? in[(b*CIN + ci)*SLEN + pos] : 0.0f;
    }
    float wreg[52];
    {
        const float4* wp = (const float4*)(cw + co*52);
        #pragma unroll
        for (int j4 = 0; j4 < 13; ++j4) {
            float4 w4 = wp[j4];
            wreg[j4*4+0]=w4.x; wreg[j4*4+1]=w4.y; wreg[j4*4+2]=w4.z; wreg[j4*4+3]=w4.w;
        }
    }
    const float scale = gamma[co] * (1.0f / sqrtf(1.0f + 1e-5f));
    const float shift = beta[co];
    __syncthreads();
    for (int si = 0; si < 16; ++si) {
        int s = s0 + si;
        if (s >= SP) break;
        float win[CIN][18];
        #pragma unroll
        for (int ci = 0; ci < CIN; ++ci)
            #pragma unroll
            for (int o = 0; o < 18; ++o)
                win[ci][o] = ins[ci][6*si + o];
        float m = -1e30f;
        #pragma unroll
        for (int p6 = 0; p6 < 6; ++p6) {
            float acc = 0.0f;
            #pragma unroll
            for (int ci = 0; ci < CIN; ++ci)
                #pragma unroll
                for (int kk = 0; kk < 13; ++kk)
                    acc += win[ci][p6+kk] * wreg[ci*13+kk];
            float val = acc * scale + shift;
            val = fmaxf(val, 0.0f);
            m = fmaxf(m, val);
        }
        x0[(size_t)(b*SP + s)*NF + co] = m;
    }
}

// ---------------------------------------------------------------------------
// Kernel 2: generic fp32 GEMM  C[M,N] = act(A[M,K] @ Bw[N,K]^T + bias[N])
// ---------------------------------------------------------------------------
template<int RELU>
__global__ __launch_bounds__(256)
void gemm_k(const float* __restrict__ A, const float* __restrict__ Bw,
            const float* __restrict__ bias, float* __restrict__ C,
            int M, int N, int K)
{
    const int n0 = blockIdx.x * 128;
    const int m0 = blockIdx.y * 128;
    const int tid = threadIdx.x;
    const int tx = tid % 16, ty = tid / 16;
    __shared__ float As[16][132];
    __shared__ float Bs[16][132];
    float acc[8][8];
    #pragma unroll
    for (int i = 0; i < 8; ++i)
        #pragma unroll
        for (int j = 0; j < 8; ++j) acc[i][j] = 0.0f;

    const int lr = tid >> 1;
    const int lc = (tid & 1) * 8;

    for (int k0 = 0; k0 < K; k0 += 16) {
        {
            int gm = m0 + lr; if (gm >= M) gm = M - 1;
            const float* ap = A + (size_t)gm*K + k0 + lc;
            float4 v0 = *(const float4*)ap;
            float4 v1 = *(const float4*)(ap + 4);
            As[lc+0][lr]=v0.x; As[lc+1][lr]=v0.y; As[lc+2][lr]=v0.z; As[lc+3][lr]=v0.w;
            As[lc+4][lr]=v1.x; As[lc+5][lr]=v1.y; As[lc+6][lr]=v1.z; As[lc+7][lr]=v1.w;
            const float* bp = Bw + (size_t)(n0 + lr)*K + k0 + lc;
            float4 u0 = *(const float4*)bp;
            float4 u1 = *(const float4*)(bp + 4);
            Bs[lc+0][lr]=u0.x; Bs[lc+1][lr]=u0.y; Bs[lc+2][lr]=u0.z; Bs[lc+3][lr]=u0.w;
            Bs[lc+4][lr]=u1.x; Bs[lc+5][lr]=u1.y; Bs[lc+6][lr]=u1.z; Bs[lc+7][lr]=u1.w;
        }
        __syncthreads();
        #pragma unroll
        for (int k = 0; k < 16; ++k) {
            float4 a0 = *(const float4*)&As[k][ty*4];
            float4 a1 = *(const float4*)&As[k][ty*4 + 64];
            float4 b0 = *(const float4*)&Bs[k][tx*4];
            float4 b1 = *(const float4*)&Bs[k][tx*4 + 64];
            float av[8] = {a0.x,a0.y,a0.z,a0.w,a1.x,a1.y,a1.z,a1.w};
            float bv[8] = {b0.x,b0.y,b0.z,b0.w,b1.x,b1.y,b1.z,b1.w};
            #pragma unroll
            for (int i = 0; i < 8; ++i)
                #pragma unroll
                for (int j = 0; j < 8; ++j)
                    acc[i][j] += av[i] * bv[j];
        }
        __syncthreads();
    }
    #pragma unroll
    for (int ih = 0; ih < 2; ++ih) {
        #pragma unroll
        for (int ii = 0; ii < 4; ++ii) {
            int m = m0 + ih*64 + ty*4 + ii;
            if (m >= M) continue;
            #pragma unroll
            for (int jh = 0; jh < 2; ++jh) {
                int n = n0 + jh*64 + tx*4;
                float4 bb = *(const float4*)&bias[n];
                float4 r;
                r.x = acc[ih*4+ii][jh*4+0] + bb.x;
                r.y = acc[ih*4+ii][jh*4+1] + bb.y;
                r.z = acc[ih*4+ii][jh*4+2] + bb.z;
                r.w = acc[ih*4+ii][jh*4+3] + bb.w;
                if (RELU) {
                    r.x = fmaxf(r.x, 0.f); r.y = fmaxf(r.y, 0.f);
                    r.z = fmaxf(r.z, 0.f); r.w = fmaxf(r.w, 0.f);
                }
                *(float4*)&C[(size_t)m*N + n] = r;
            }
        }
    }
}

// ---------------------------------------------------------------------------
// Kernel 3a: pack fp32 weights -> bf16 hi/lo pair (same row-major layout)
// ---------------------------------------------------------------------------
__global__ __launch_bounds__(256)
void pack_whh_k(const float* __restrict__ W, unsigned short* __restrict__ hi,
                unsigned short* __restrict__ lo, int n)
{
    int i = blockIdx.x * 256 + threadIdx.x;
    if (i < n) {
        float x = W[i];
        unsigned short h = f2bf(x);
        hi[i] = h;
        lo[i] = f2bf(x - bf2f(h));
    }
}

// ---------------------------------------------------------------------------
// Kernel 3b: PERSISTENT LSTM scan (one launch per layer). Grid (8,11,2)=176
// blocks; 148 KB LDS -> 1 block/CU, co-resident (proven R7-R9). W slice in LDS
// in fragment order [gp(32768)][t(8192)][kk(1024)][p(512)][lane(8)].
// R11 barrier: R9's 88 serialized agent-scope fetch_adds on one line (~13us of
// the 16us/step residual) replaced by: per-block release STORE to a 32B-strided
// flag (value s+1, monotonic, no reset) -> one master block per direction
// aggregates all 88 flags with a single wave-wide load (__all ballot) and
// release-stores go[d]=s+1 -> spinners poll go relaxed, ONE acquire at exit
// (release->acquire transitivity covers h visibility). Barrier skipped on the
// final step.
// ---------------------------------------------------------------------------
__global__ __launch_bounds__(256, 1)
void lstm_scan_k(const float* __restrict__ G,              // [32*341][2048]
                 const unsigned short* __restrict__ Whi,   // [2][1024][256]
                 const unsigned short* __restrict__ Wlo,
                 float* __restrict__ h_buf,                // [2 parity][2 dir][341][256]
                 float* __restrict__ x_out,                // [32*341][512]
                 int* __restrict__ bar)                    // flags: [2][88]*8 ints, go at [1408+d]
{
    __shared__ unsigned short wl[65536];   // 128 KB
    __shared__ float Csh[32][132];         // 16.9 KB

    const int j0 = blockIdx.x * 32;
    const int m0 = blockIdx.y * 32;
    const int d  = blockIdx.z;
    const int tid = threadIdx.x;
    const int w = tid >> 6, lane = tid & 63;
    const int mhalf = w & 1, gpair = w >> 1;
    const int ln15 = lane & 15, lq = lane >> 4;
    const int fb = blockIdx.y*8 + blockIdx.x;   // [0,88) flag index within direction

    // ---- one-time W preload into LDS (fragment order) ----
    {
        const unsigned short* WhiD = Whi + (size_t)d*1024*256;
        const unsigned short* WloD = Wlo + (size_t)d*1024*256;
        for (int idx = tid; idx < 8192; idx += 256) {
            int lane_ = idx & 63;
            int p     = (idx >> 6) & 1;
            int kk_   = (idx >> 7) & 7;
            int t_    = (idx >> 10) & 3;
            int gp_   = (idx >> 12) & 1;
            int l15 = lane_ & 15, lq_ = lane_ >> 4;
            int grow = (gp_*2 + (t_>>1))*256 + j0 + (t_&1)*16 + l15;  // global gate-row
            int kb   = kk_*32 + lq_*8;
            const unsigned short* src = (p ? WloD : WhiD) + (size_t)grow*HD + kb;
            unsigned short* dst = wl + ((size_t)((((gp_*4 + t_)*8 + kk_)*2 + p)*64 + lane_) * 8);
            *(uint4*)dst = *(const uint4*)src;
        }
    }
    __syncthreads();

    int am = m0 + mhalf*16 + ln15; if (am > SP-1) am = SP-1;   // A row (clamped)
    const int akoff = lq * 8;
    // this wave's B-frag base: frag(t,kk,p) at wbase + ((t*8+kk)*2+p)*512; gp stride 32768
    const unsigned short* wbase = wl + (size_t)gpair*32768 + (size_t)lane*8;

    const int emloc = tid >> 3;           // 0..31 local row
    const int ej4   = (tid & 7) * 4;      // 0..28 local col (x4)
    const int em    = m0 + emloc;

    float4 creg = {0.f, 0.f, 0.f, 0.f};   // persistent c state for (em, j0+ej4..+3)

    for (int s = 0; s < B_; ++s) {
        const int t_in = d ? (B_ - 1 - s) : s;
        const float* hA = h_buf + (size_t)(s & 1)*2*HS + (size_t)d*HS + (size_t)am*HD;

        floatx4 acc[4];
        #pragma unroll
        for (int t = 0; t < 4; ++t) acc[t] = (floatx4){0.f, 0.f, 0.f, 0.f};

        #pragma unroll
        for (int kk = 0; kk < 8; ++kk) {
            const int ko = kk*32 + akoff;
            float4 v0 = *(const float4*)(hA + ko);
            float4 v1 = *(const float4*)(hA + ko + 4);
            float vv[8] = {v0.x, v0.y, v0.z, v0.w, v1.x, v1.y, v1.z, v1.w};
            short8 ahi, alo;
            #pragma unroll
            for (int e = 0; e < 8; ++e) {
                unsigned short hb16 = f2bf(vv[e]);
                ahi[e] = (short)hb16;
                alo[e] = (short)f2bf(vv[e] - bf2f(hb16));
            }
            #pragma unroll
            for (int t = 0; t < 4; ++t) {
                short8 bhi = *(const short8*)(wbase + ((t*8 + kk)*2 + 0)*512);
                short8 blo = *(const short8*)(wbase + ((t*8 + kk)*2 + 1)*512);
                acc[t] = __builtin_amdgcn_mfma_f32_16x16x32_bf16(alo, bhi, acc[t], 0, 0, 0);
                acc[t] = __builtin_amdgcn_mfma_f32_16x16x32_bf16(ahi, blo, acc[t], 0, 0, 0);
                acc[t] = __builtin_amdgcn_mfma_f32_16x16x32_bf16(ahi, bhi, acc[t], 0, 0, 0);
            }
        }

        // dump C fragments to LDS (D: col=lane&15, row=lq*4+reg)
        #pragma unroll
        for (int t = 0; t < 4; ++t) {
            int col = gpair*64 + (t>>1)*32 + (t&1)*16 + ln15;
            int rb  = mhalf*16 + lq*4;
            #pragma unroll
            for (int r = 0; r < 4; ++r)
                Csh[rb + r][col] = acc[t][r];
        }
        __syncthreads();

        if (em < SP) {
            size_t gb = ((size_t)t_in*SP + em)*2048 + (size_t)d*1024 + j0 + ej4;
            float4 gi4 = *(const float4*)&G[gb];
            float4 gf4 = *(const float4*)&G[gb + 256];
            float4 gg4 = *(const float4*)&G[gb + 512];
            float4 go4 = *(const float4*)&G[gb + 768];
            float hv[4];
            #pragma unroll
            for (int e = 0; e < 4; ++e) {
                float gi = Csh[emloc][     ej4+e] + (&gi4.x)[e];
                float gf = Csh[emloc][32 + ej4+e] + (&gf4.x)[e];
                float gg = Csh[emloc][64 + ej4+e] + (&gg4.x)[e];
                float go = Csh[emloc][96 + ej4+e] + (&go4.x)[e];
                float cn = sigmoidf_(gf)*(&creg.x)[e] + sigmoidf_(gi)*tanhf(gg);
                (&creg.x)[e] = cn;
                hv[e] = sigmoidf_(go)*tanhf(cn);
            }
            float4 ho; ho.x = hv[0]; ho.y = hv[1]; ho.z = hv[2]; ho.w = hv[3];
            size_t hbase = ((size_t)d*SP + em)*HD + j0 + ej4;
            *(float4*)&h_buf[(size_t)((s+1) & 1)*2*HS + hbase] = ho;
            *(float4*)&x_out[((size_t)t_in*SP + em)*512 + d*HD + j0 + ej4] = ho;
        }
        __syncthreads();

        if (s == B_-1) break;   // no one reads h after the last step

        // ---- serialization-free per-direction device barrier ----
        if (tid == 0)   // arrival: concurrent release store to own 32B-strided flag
            __hip_atomic_store(&bar[(d*88 + fb)*8], s+1, __ATOMIC_RELEASE, __HIP_MEMORY_SCOPE_AGENT);
        if (fb == 0 && tid < 64) {   // master wave: aggregate 88 flags in one wide load
            const int ia = tid, ib = 64 + tid;
            for (;;) {
                int va = __hip_atomic_load(&bar[(d*88 + ia)*8], __ATOMIC_RELAXED, __HIP_MEMORY_SCOPE_AGENT);
                int vb = (ib < 88) ? __hip_atomic_load(&bar[(d*88 + ib)*8], __ATOMIC_RELAXED, __HIP_MEMORY_SCOPE_AGENT)
                                   : (s+1);
                if (__all(va >= s+1 && vb >= s+1)) break;
                __builtin_amdgcn_s_sleep(1);
            }
            if (tid == 0)
                __hip_atomic_store(&bar[1408 + d], s+1, __ATOMIC_RELEASE, __HIP_MEMORY_SCOPE_AGENT);
        }
        if (tid == 0) {   // everyone (incl. master) waits for go, then ONE acquire
            while (__hip_atomic_load(&bar[1408 + d], __ATOMIC_RELAXED, __HIP_MEMORY_SCOPE_AGENT) < s+1)
                __builtin_amdgcn_s_sleep(1);
            (void)__hip_atomic_load(&bar[1408 + d], __ATOMIC_ACQUIRE, __HIP_MEMORY_SCOPE_AGENT);
        }
        __syncthreads();
    }
}

// ---------------------------------------------------------------------------
// Kernel 4a: scores tile (64x64), RPE analytic.
// ---------------------------------------------------------------------------
__global__ __launch_bounds__(256)
void scores_k(const float* __restrict__ q, const float* __restrict__ k,
              float* __restrict__ P, int g)
{
    const int h = blockIdx.z, bl = blockIdx.y, bg = g*GRP + bl;
    const int q0 = (blockIdx.x / 6) * 64;
    const int k0 = (blockIdx.x % 6) * 64;
    const int tid = threadIdx.x;
    __shared__ float qs[64][68];
    __shared__ float ks[64][68];
    {
        int jr = tid >> 2, c16 = (tid & 3) * 16;
        int qq = q0 + jr; if (qq > SP-1) qq = SP-1;
        int kr = k0 + jr; if (kr > SP-1) kr = SP-1;
        const float* qp = &q[((size_t)bg*SP + qq)*512 + h*64 + c16];
        const float* kp = &k[((size_t)bg*SP + kr)*512 + h*64 + c16];
        #pragma unroll
        for (int u = 0; u < 4; ++u) {
            *(float4*)&qs[jr][c16 + u*4] = *(const float4*)(qp + u*4);
            *(float4*)&ks[jr][c16 + u*4] = *(const float4*)(kp + u*4);
        }
    }
    __syncthreads();
    const int tx = tid & 15, ty = tid >> 4;
    float acc[4][4];
    #pragma unroll
    for (int i = 0; i < 4; ++i)
        #pragma unroll
        for (int j = 0; j < 4; ++j) acc[i][j] = 0.0f;
    for (int d4 = 0; d4 < 64; d4 += 4) {
        float4 a[4], b[4];
        #pragma unroll
        for (int i = 0; i < 4; ++i) a[i] = *(const float4*)&qs[ty + 16*i][d4];
        #pragma unroll
        for (int j = 0; j < 4; ++j) b[j] = *(const float4*)&ks[tx + 16*j][d4];
        #pragma unroll
        for (int i = 0; i < 4; ++i)
            #pragma unroll
            for (int j = 0; j < 4; ++j)
                acc[i][j] += a[i].x*b[j].x + a[i].y*b[j].y + a[i].z*b[j].z + a[i].w*b[j].w;
    }
    #pragma unroll
    for (int i = 0; i < 4; ++i) {
        int qq = q0 + ty + 16*i;
        if (qq >= SP) continue;
        int r0 = 6*qq - 1; if (r0 < 0) r0 = 0;
        int r1 = 6*qq + 7; if (r1 > SLEN-1) r1 = SLEN-1;
        size_t rowb = ((size_t)(h*GRP + bl)*SP + qq) * PSTR;
        #pragma unroll
        for (int j = 0; j < 4; ++j) {
            int kk = k0 + tx + 16*j;
            if (kk >= SP) continue;
            int c0 = 6*kk - 1; if (c0 < 0) c0 = 0;
            int c1 = 6*kk + 7;
            int dd1 = c1 - r0; if (dd1 < 0) dd1 = -dd1;
            int dd2 = r1 - c0; if (dd2 < 0) dd2 = -dd2;
            int den = dd1 > dd2 ? dd1 : dd2;
            P[rowb + kk] = (acc[i][j] * 0.125f) * 2047.0f / (float)den;
        }
    }
}

// ---------------------------------------------------------------------------
// Kernel 4b: row softmax in place.
// ---------------------------------------------------------------------------
__global__ __launch_bounds__(256)
void softmax_k(float* __restrict__ P)
{
    const int tid = threadIdx.x;
    const int row = blockIdx.x * 4 + (tid >> 6);
    const int lane = tid & 63;
    float* rp = P + (size_t)row * PSTR;
    float v[6];
    float m = -1e30f;
    #pragma unroll
    for (int i = 0; i < 6; ++i) {
        int col = lane + 64*i;
        v[i] = (col < SP) ? rp[col] : -1e30f;
        m = fmaxf(m, v[i]);
    }
    #pragma unroll
    for (int o = 1; o < 64; o <<= 1) m = fmaxf(m, __shfl_xor(m, o, 64));
    float s = 0.0f;
    #pragma unroll
    for (int i = 0; i < 6; ++i) {
        v[i] = expf(v[i] - m);
        s += v[i];
    }
    #pragma unroll
    for (int o = 1; o < 64; o <<= 1) s += __shfl_xor(s, o, 64);
    float inv = 1.0f / s;
    #pragma unroll
    for (int i = 0; i < 6; ++i) {
        int col = lane + 64*i;
        if (col < SP) rp[col] = v[i] * inv;
    }
}

// ---------------------------------------------------------------------------
// Kernel 4c: out = relu(P @ V), K=SP in 6x64 chunks.
// ---------------------------------------------------------------------------
__global__ __launch_bounds__(256)
void pv_k(const float* __restrict__ P, const float* __restrict__ v,
          float* __restrict__ cat, int g)
{
    const int h = blockIdx.z, bl = blockIdx.y, bg = g*GRP + bl;
    const int q0 = blockIdx.x * 64;
    const int tid = threadIdx.x;
    __shared__ float ps[64][68];
    __shared__ float vs[64][68];
    const int tx = tid & 15, ty = tid >> 4;
    float acc[4][4];
    #pragma unroll
    for (int i = 0; i < 4; ++i)
        #pragma unroll
        for (int j = 0; j < 4; ++j) acc[i][j] = 0.0f;

    for (int kc = 0; kc < 6; ++kc) {
        const int kk0 = kc * 64;
        {
            int jr = tid >> 2, c16 = (tid & 3) * 16;
            int qq = q0 + jr; if (qq > SP-1) qq = SP-1;
            const float* pp = P + ((size_t)(h*GRP + bl)*SP + qq)*PSTR + kk0 + c16;
            #pragma unroll
            for (int u = 0; u < 4; ++u) {
                float4 w = *(const float4*)(pp + u*4);
                int klb = c16 + u*4;
                float vals[4] = {w.x, w.y, w.z, w.w};
                #pragma unroll
                for (int e = 0; e < 4; ++e)
                    ps[klb + e][jr] = (kk0 + klb + e < SP) ? vals[e] : 0.0f;
            }
        }
        {
            int jr = tid >> 2, c16 = (tid & 3) * 16;
            int kr = kk0 + jr; if (kr > SP-1) kr = SP-1;
            const float* vp = &v[((size_t)bg*SP + kr)*512 + h*64 + c16];
            #pragma unroll
            for (int u = 0; u < 4; ++u)
                *(float4*)&vs[jr][c16 + u*4] = *(const float4*)(vp + u*4);
        }
        __syncthreads();
        for (int kk = 0; kk < 64; ++kk) {
            float4 a4 = *(const float4*)&ps[kk][ty*4];
            float4 b4 = *(const float4*)&vs[kk][tx*4];
            float av[4] = {a4.x, a4.y, a4.z, a4.w};
            float bv[4] = {b4.x, b4.y, b4.z, b4.w};
            #pragma unroll
            for (int i = 0; i < 4; ++i)
                #pragma unroll
                for (int j = 0; j < 4; ++j)
                    acc[i][j] += av[i] * bv[j];
        }
        __syncthreads();
    }
    #pragma unroll
    for (int i = 0; i < 4; ++i) {
        int qq = q0 + ty*4 + i;
        if (qq >= SP) continue;
        float4 r;
        r.x = fmaxf(acc[i][0], 0.0f);
        r.y = fmaxf(acc[i][1], 0.0f);
        r.z = fmaxf(acc[i][2], 0.0f);
        r.w = fmaxf(acc[i][3], 0.0f);
        *(float4*)&cat[((size_t)bg*SP + qq)*512 + h*64 + tx*4] = r;
    }
}

// ---------------------------------------------------------------------------
extern "C" void kernel_launch(void* const* d_in, const int* in_sizes, int n_in,
                              void* d_out, int out_size, void* d_ws, size_t ws_size,
                              hipStream_t stream)
{
    (void)in_sizes; (void)n_in; (void)out_size; (void)ws_size;
    const float* in    = (const float*)d_in[0];
    const float* cw    = (const float*)d_in[1];
    const float* gamma = (const float*)d_in[2];
    const float* beta  = (const float*)d_in[3];
    const float* Wih0  = (const float*)d_in[4];
    const float* Whh0  = (const float*)d_in[5];
    const float* b0    = (const float*)d_in[6];
    const float* Wih1  = (const float*)d_in[7];
    const float* Whh1  = (const float*)d_in[8];
    const float* b1    = (const float*)d_in[9];
    const float* Qw    = (const float*)d_in[10];
    const float* Qb    = (const float*)d_in[11];
    const float* Kw    = (const float*)d_in[12];
    const float* Kb    = (const float*)d_in[13];
    const float* Vw    = (const float*)d_in[14];
    const float* Vb    = (const float*)d_in[15];
    const float* mhw   = (const float*)d_in[16];
    const float* mhb   = (const float*)d_in[17];
    float* out = (float*)d_out;

    // workspace arena (floats). Total 147.36 MB — EXACT R3/R6 memory map.
    float* x0 = (float*)d_ws;                                   //  2,793,472 f (packs + bar live here after use)
    float* G  = x0 + (size_t)RTOT*NF;                           // 22,347,776 f (reused q,k,v + P)
    float* x1 = G  + (size_t)RTOT*2048;                         //  5,586,944 f (reused cat)
    float* x2 = x1 + (size_t)RTOT*512;                          //  5,586,944 f
    float* hb = x2 + (size_t)RTOT*512;                          //  349,184 f (fp32 h parity buffers)
    float* cb = hb + (size_t)2*2*SP*HD;                         //  174,592 f (unused now)
    (void)cb;
    // Whh bf16 hi/lo pack arrays in x0's space (x0 dead after the first G-GEMM):
    unsigned short* whh_hi0 = (unsigned short*)x0;              // 524,288 ush each
    unsigned short* whh_lo0 = whh_hi0 + (size_t)2*1024*256;
    unsigned short* whh_hi1 = whh_lo0 + (size_t)2*1024*256;
    unsigned short* whh_lo1 = whh_hi1 + (size_t)2*1024*256;     // 4.19 MB < x0's 11.17 MB
    int* bar = (int*)(x0 + 1200000);                            // flags [2][88]*8 + go[2] (dead x0 space)
    float* qbuf = G;
    float* kbuf = G + (size_t)RTOT*512;
    float* vbuf = G + (size_t)2*RTOT*512;
    float* P    = G + (size_t)3*RTOT*512;
    float* cat  = x1;
    const size_t hsz = (size_t)2*SP*HD;
    const size_t barsz = (size_t)(1408 + 2) * sizeof(int);

    // 1. conv+bn+relu+pool
    conv_pool_k<<<dim3(22, B_), 256, 0, stream>>>(in, cw, gamma, beta, x0);
    // 2. layer-1 input gates: G = x0 @ Wih0^T + b0  (consumes x0)
    gemm_k<0><<<dim3(16, 86), 256, 0, stream>>>(x0, Wih0, b0, G, RTOT, 2048, 256);
    // 2b. pack Whh -> bf16 hi/lo into x0's space (stream-ordered after gemm#1)
    pack_whh_k<<<dim3(2048), 256, 0, stream>>>(Whh0, whh_hi0, whh_lo0, 2*1024*256);
    pack_whh_k<<<dim3(2048), 256, 0, stream>>>(Whh1, whh_hi1, whh_lo1, 2*1024*256);
    // 3. layer-1 persistent scan
    hipMemsetAsync(hb, 0, hsz*sizeof(float), stream);           // parity-0 h
    hipMemsetAsync(bar, 0, barsz, stream);
    lstm_scan_k<<<dim3(8, 11, 2), 256, 0, stream>>>(G, whh_hi0, whh_lo0, hb, x1, bar);
    // 4. layer-2 input gates
    gemm_k<0><<<dim3(16, 86), 256, 0, stream>>>(x1, Wih1, b1, G, RTOT, 2048, 512);
    // 5. layer-2 persistent scan
    hipMemsetAsync(hb, 0, hsz*sizeof(float), stream);
    hipMemsetAsync(bar, 0, barsz, stream);
    lstm_scan_k<<<dim3(8, 11, 2), 256, 0, stream>>>(G, whh_hi1, whh_lo1, hb, x2, bar);
    // 6. Q/K/V projections
    gemm_k<0><<<dim3(4, 86), 256, 0, stream>>>(x2, Qw, Qb, qbuf, RTOT, 512, 512);
    gemm_k<0><<<dim3(4, 86), 256, 0, stream>>>(x2, Kw, Kb, kbuf, RTOT, 512, 512);
    gemm_k<0><<<dim3(4, 86), 256, 0, stream>>>(x2, Vw, Vb, vbuf, RTOT, 512, 512);
    // 7. attention in GRP-batch groups
    for (int g = 0; g < B_/GRP; ++g) {
        scores_k <<<dim3(36, GRP, NH_), 256, 0, stream>>>(qbuf, kbuf, P, g);
        softmax_k<<<dim3(NH_*GRP*SP/4), 256, 0, stream>>>(P);
        pv_k     <<<dim3(6, GRP, NH_), 256, 0, stream>>>(P, vbuf, cat, g);
    }
    // 8. final linear + relu
    gemm_k<1><<<dim3(4, 86), 256, 0, stream>>>(cat, mhw, mhb, out, RTOT, 512, 512);
}